// Round 1
// baseline (12.757 us; speedup 1.0000x reference)
//
#include <hip/hip_runtime.h>

#define G0 64
#define G1 64
#define HH 512
#define WW 512
#define CC 8

__global__ __launch_bounds__(256) void ImageInterpolator_kernel(
    const float* __restrict__ image,
    const float* __restrict__ section,
    float* __restrict__ out)
{
    const int idx = blockIdx.x * 256 + threadIdx.x;   // 0 .. 64*64*64-1
    const int g1 = idx & 63;
    const int g0 = (idx >> 6) & 63;
    const int b  = idx >> 12;

    const float s0 = section[b * 3 + 0];
    const float s1 = section[b * 3 + 1];
    const float sz = section[b * 3 + 2];

    const float step = 1.0f / 63.0f;           // linspace(0,1,64) step
    const float q0 = s0 + ((float)g0 * step) * sz;
    const float q1 = s1 + ((float)g1 * step) * sz;

    const float i0 = fminf(fmaxf(q0 * 511.0f, 0.0f), 511.0f);
    const float i1 = fminf(fmaxf(q1 * 511.0f, 0.0f), 511.0f);
    const float f0 = floorf(i0);
    const float f1 = floorf(i1);
    const float w0 = i0 - f0;
    const float w1 = i1 - f1;

    const int lo0 = (int)f0;
    const int lo1 = (int)f1;
    const int hi0 = min(lo0 + 1, HH - 1);
    const int hi1 = min(lo1 + 1, WW - 1);

    const float* base = image + (size_t)b * HH * WW * CC;
    const float4* plo_lo = (const float4*)(base + ((size_t)lo0 * WW + lo1) * CC);
    const float4* plo_hi = (const float4*)(base + ((size_t)lo0 * WW + hi1) * CC);
    const float4* phi_lo = (const float4*)(base + ((size_t)hi0 * WW + lo1) * CC);
    const float4* phi_hi = (const float4*)(base + ((size_t)hi0 * WW + hi1) * CC);

    const float om0 = 1.0f - w0;
    const float om1 = 1.0f - w1;

    float4* o = (float4*)(out + (size_t)idx * CC);
#pragma unroll
    for (int h = 0; h < 2; ++h) {
        const float4 v00 = plo_lo[h];
        const float4 v01 = plo_hi[h];
        const float4 v10 = phi_lo[h];
        const float4 v11 = phi_hi[h];
        float4 r;
        r.x = (v00.x * om1 + v01.x * w1) * om0 + (v10.x * om1 + v11.x * w1) * w0;
        r.y = (v00.y * om1 + v01.y * w1) * om0 + (v10.y * om1 + v11.y * w1) * w0;
        r.z = (v00.z * om1 + v01.z * w1) * om0 + (v10.z * om1 + v11.z * w1) * w0;
        r.w = (v00.w * om1 + v01.w * w1) * om0 + (v10.w * om1 + v11.w * w1) * w0;
        o[h] = r;
    }
}

extern "C" void kernel_launch(void* const* d_in, const int* in_sizes, int n_in,
                              void* d_out, int out_size, void* d_ws, size_t ws_size,
                              hipStream_t stream) {
    const float* image   = (const float*)d_in[0];
    const float* section = (const float*)d_in[1];
    float* out = (float*)d_out;

    const int total = 64 * G0 * G1;            // threads = output pixels
    const int threads = 256;
    const int blocks = total / threads;        // 1024
    ImageInterpolator_kernel<<<blocks, threads, 0, stream>>>(image, section, out);
}

// Round 2
// 10.931 us; speedup vs baseline: 1.1670x; 1.1670x over previous
//
#include <hip/hip_runtime.h>

#define G0 64
#define G1 64
#define HH 512
#define WW 512
#define CC 8

// One thread per half-pixel (float4 of 4 channels). 524288 threads total.
// b is derived from blockIdx only -> block-uniform -> scalar s_load of section.
__global__ __launch_bounds__(256) void ImageInterpolator_kernel(
    const float* __restrict__ image,
    const float* __restrict__ section,
    float* __restrict__ out)
{
    const int idx = blockIdx.x * 256 + threadIdx.x;   // 0 .. 64*64*64*2-1
    const int h  = idx & 1;                            // channel half
    const int g1 = (idx >> 1) & 63;
    const int g0 = (idx >> 7) & 63;
    const int b  = blockIdx.x >> 5;                    // 32 blocks per batch (block-uniform)

    const float s0 = section[b * 3 + 0];
    const float s1 = section[b * 3 + 1];
    const float sz = section[b * 3 + 2];

    const float step = 1.0f / 63.0f;                   // linspace(0,1,64) step
    const float q0 = s0 + ((float)g0 * step) * sz;
    const float q1 = s1 + ((float)g1 * step) * sz;

    const float i0 = fminf(fmaxf(q0 * 511.0f, 0.0f), 511.0f);
    const float i1 = fminf(fmaxf(q1 * 511.0f, 0.0f), 511.0f);
    const float f0 = floorf(i0);
    const float f1 = floorf(i1);
    const float w0 = i0 - f0;
    const float w1 = i1 - f1;

    const int lo0 = (int)f0;
    const int lo1 = (int)f1;
    const int hi0 = min(lo0 + 1, HH - 1);
    const int hi1 = min(lo1 + 1, WW - 1);

    const float* base = image + (size_t)b * HH * WW * CC + (h << 2);
    const float4 v00 = *(const float4*)(base + ((size_t)lo0 * WW + lo1) * CC);
    const float4 v01 = *(const float4*)(base + ((size_t)lo0 * WW + hi1) * CC);
    const float4 v10 = *(const float4*)(base + ((size_t)hi0 * WW + lo1) * CC);
    const float4 v11 = *(const float4*)(base + ((size_t)hi0 * WW + hi1) * CC);

    const float om0 = 1.0f - w0;
    const float om1 = 1.0f - w1;

    float4 r;
    r.x = (v00.x * om1 + v01.x * w1) * om0 + (v10.x * om1 + v11.x * w1) * w0;
    r.y = (v00.y * om1 + v01.y * w1) * om0 + (v10.y * om1 + v11.y * w1) * w0;
    r.z = (v00.z * om1 + v01.z * w1) * om0 + (v10.z * om1 + v11.z * w1) * w0;
    r.w = (v00.w * om1 + v01.w * w1) * om0 + (v10.w * om1 + v11.w * w1) * w0;

    *(float4*)(out + (size_t)idx * 4) = r;
}

extern "C" void kernel_launch(void* const* d_in, const int* in_sizes, int n_in,
                              void* d_out, int out_size, void* d_ws, size_t ws_size,
                              hipStream_t stream) {
    const float* image   = (const float*)d_in[0];
    const float* section = (const float*)d_in[1];
    float* out = (float*)d_out;

    const int total = 64 * G0 * G1 * 2;        // half-pixels
    const int threads = 256;
    const int blocks = total / threads;        // 2048
    ImageInterpolator_kernel<<<blocks, threads, 0, stream>>>(image, section, out);
}